// Round 7
// baseline (344.411 us; speedup 1.0000x reference)
//
#include <hip/hip_runtime.h>
#include <math.h>

// ---------------------------------------------------------------------------
// EG-GAT layer v7 — one-wave-per-node fused kernel (2 output cols per lane):
//   K1 hproj+hist: h16[N,128] (f16) = x @ W_node; grid-stride degree histogram
//   K2 alloc:      CSR segment starts (wave-aggregated cursor)
//   K3 scatter:    csr[pos] = (e<<5, src<<8); ea -> ea16 (f16, edge order)
//   K4 fused2:     wave per node, lane = head*8+dd covers d = 2dd, 2dd+1.
//                  Per edge: packed fdot2 logit partial + 3-step shfl_xor,
//                  16 fdot2 gate (2 cols), den += pa in-loop, float2 store.
// ---------------------------------------------------------------------------

#define LOG2E 1.44269504088896340736f

typedef _Float16 h2 __attribute__((ext_vector_type(2)));
typedef _Float16 h4 __attribute__((ext_vector_type(4)));

__device__ __forceinline__ float fdot2(h2 a, h2 b, float c) {
    return __builtin_amdgcn_fdot2(a, b, c, false);
}
__device__ __forceinline__ h2 bch(unsigned u) {
    return __builtin_bit_cast(h2, u);
}

// K1: register-blocked GEMM (f16 out) + degree histogram.
__global__ __launch_bounds__(256) void k_hproj(
    const float* __restrict__ x, const float* __restrict__ Wn,
    _Float16* __restrict__ h16, int N,
    const int* __restrict__ dst, int* __restrict__ counts, int E)
{
    // histogram (grid-stride; atomics overlap the GEMM below)
    int tid = blockIdx.x * 256 + threadIdx.x;
    int tot = gridDim.x * 256;
    for (int e = tid; e < E; e += tot) atomicAdd(counts + dst[e], 1);

    int t  = threadIdx.x;
    int cg = t & 31, rg = t >> 5;
    int c0 = cg * 4;
    int hh = c0 >> 4, d0 = c0 & 15;
    int r0 = blockIdx.x * 64 + rg * 8;
    const float* wbase = Wn + hh * 2048 + d0;

    float acc[8][4];
#pragma unroll
    for (int j = 0; j < 8; ++j)
#pragma unroll
        for (int q = 0; q < 4; ++q) acc[j][q] = 0.f;

    int rr[8];
#pragma unroll
    for (int j = 0; j < 8; ++j) { int n = r0 + j; rr[j] = (n < N) ? n : (N - 1); }

    for (int k0 = 0; k0 < 128; k0 += 4) {
        float4 b0 = *(const float4*)(wbase + (k0 + 0) * 16);
        float4 b1 = *(const float4*)(wbase + (k0 + 1) * 16);
        float4 b2 = *(const float4*)(wbase + (k0 + 2) * 16);
        float4 b3 = *(const float4*)(wbase + (k0 + 3) * 16);
#pragma unroll
        for (int j = 0; j < 8; ++j) {
            float4 a = *(const float4*)(x + (size_t)rr[j] * 128 + k0);
            acc[j][0] += a.x * b0.x + a.y * b1.x + a.z * b2.x + a.w * b3.x;
            acc[j][1] += a.x * b0.y + a.y * b1.y + a.z * b2.y + a.w * b3.y;
            acc[j][2] += a.x * b0.z + a.y * b1.z + a.z * b2.z + a.w * b3.z;
            acc[j][3] += a.x * b0.w + a.y * b1.w + a.z * b2.w + a.w * b3.w;
        }
    }
#pragma unroll
    for (int j = 0; j < 8; ++j) {
        int n = r0 + j;
        if (n < N) {
            h4 v = { (_Float16)acc[j][0], (_Float16)acc[j][1],
                     (_Float16)acc[j][2], (_Float16)acc[j][3] };
            *(h4*)(h16 + (size_t)n * 128 + c0) = v;
        }
    }
}

__global__ __launch_bounds__(256) void k_alloc(
    const int* __restrict__ counts, int* __restrict__ start,
    int* __restrict__ cursor, int* __restrict__ gcur, int N)
{
    int i = blockIdx.x * 256 + threadIdx.x;
    int lane = threadIdx.x & 63;
    int v = (i < N) ? counts[i] : 0;
    int incl = v;
#pragma unroll
    for (int o = 1; o < 64; o <<= 1) {
        int u = __shfl_up(incl, o);
        if (lane >= o) incl += u;
    }
    int total = __shfl(incl, 63);
    int base = 0;
    if (lane == 63) base = atomicAdd(gcur, total);
    base = __shfl(base, 63);
    int st = base + incl - v;
    if (i < N) { start[i] = st; cursor[i] = st; }
}

// K3: bucket edges by dst (byte offsets) + ea f32->f16 conversion (edge order).
__global__ __launch_bounds__(256) void k_scatter(
    const int* __restrict__ src, const int* __restrict__ dst,
    const float* __restrict__ ea, int* __restrict__ cursor,
    int2* __restrict__ csr, _Float16* __restrict__ ea16, int E)
{
    int e = blockIdx.x * 256 + threadIdx.x;
    if (e >= E) return;
    int dn = dst[e];
    int pos = atomicAdd(cursor + dn, 1);
    csr[pos] = make_int2(e << 5, src[e] << 8);
    const float4* ap = (const float4*)(ea + (size_t)e * 16);
    float4 a0 = ap[0], a1 = ap[1], a2 = ap[2], a3 = ap[3];
    h4* op = (h4*)(ea16 + (size_t)e * 16);
    op[0] = h4{(_Float16)a0.x, (_Float16)a0.y, (_Float16)a0.z, (_Float16)a0.w};
    op[1] = h4{(_Float16)a1.x, (_Float16)a1.y, (_Float16)a1.z, (_Float16)a1.w};
    op[2] = h4{(_Float16)a2.x, (_Float16)a2.y, (_Float16)a2.z, (_Float16)a2.w};
    op[3] = h4{(_Float16)a3.x, (_Float16)a3.y, (_Float16)a3.z, (_Float16)a3.w};
}

// K4: one wave per node (2 nodes sequentially per wave), 2 cols per lane.
__global__ __launch_bounds__(256) void k_fused2(
    const _Float16* __restrict__ h16, const _Float16* __restrict__ ea16,
    const float* __restrict__ We, const int2* __restrict__ csr,
    const int* __restrict__ start, const int* __restrict__ counts,
    float* __restrict__ out, int N)
{
    int lane = threadIdx.x & 63;
    int wid  = threadIdx.x >> 6;            // wave id in block: 0..3
    int head = lane >> 3, dd = lane & 7;
    int d0 = dd * 2;                        // output cols d0, d0+1

    // gate columns We[head][:, d0] and [:, d0+1], packed in pairs along i
    const float* Wh = We + head * 256;
    h2 wa[8], wb[8];
#pragma unroll
    for (int i = 0; i < 8; ++i) {
        wa[i] = h2{ (_Float16)Wh[(2*i)*16 + d0],     (_Float16)Wh[(2*i+1)*16 + d0] };
        wb[i] = h2{ (_Float16)Wh[(2*i)*16 + d0 + 1], (_Float16)Wh[(2*i+1)*16 + d0 + 1] };
    }
    // colsum pair: cs[h,i] = sum_d We[h][i][d], lane covers i = d0, d0+1
    float cs0 = 0.f, cs1 = 0.f;
#pragma unroll
    for (int k = 0; k < 16; ++k) { cs0 += Wh[d0 * 16 + k]; cs1 += Wh[(d0 + 1) * 16 + k]; }
    h2 cs2 = h2{ (_Float16)cs0, (_Float16)cs1 };

    const char* hb = (const char*)h16;
    const char* eb = (const char*)ea16;
    int nodebase = (blockIdx.x * 4 + wid) * 2;

#pragma unroll
    for (int nn = 0; nn < 2; ++nn) {
        int n = nodebase + nn;
        if (n >= N) break;

        h2 q2 = *(const h2*)(hb + ((size_t)n << 8) + (lane << 2));
        int deg = counts[n], s0 = start[n];

        float acc0 = 0.f, acc1 = 0.f, den = 0.f;
        if (deg > 0) {
            int dm1 = deg - 1;
            int2 ceA = csr[s0];
            h2   kvA = *(const h2*)(hb + (unsigned)ceA.y + (lane << 2));
            uint4 r0A = *(const uint4*)(eb + (unsigned)ceA.x);
            uint4 r1A = *(const uint4*)(eb + (unsigned)ceA.x + 16);
            h2   eaA = *(const h2*)(eb + (unsigned)ceA.x + (dd << 2));

            int j1 = (1 < dm1) ? 1 : dm1;
            int2 ceB = csr[s0 + j1];

            for (int j = 0; j < deg; ++j) {
                // loads for edge j+1 (clamped at tail)
                h2   kvB = *(const h2*)(hb + (unsigned)ceB.y + (lane << 2));
                uint4 r0B = *(const uint4*)(eb + (unsigned)ceB.x);
                uint4 r1B = *(const uint4*)(eb + (unsigned)ceB.x + 16);
                h2   eaB = *(const h2*)(eb + (unsigned)ceB.x + (dd << 2));
                int jc = j + 2; jc = (jc < dm1) ? jc : dm1;
                int2 ceC = csr[s0 + jc];

                // logit: packed partial (q.k pair + colsum pair), 3-step tree
                float part = fdot2(q2, kvA, 0.f);
                part = fdot2(eaA, cs2, part);
                part += __shfl_xor(part, 1);
                part += __shfl_xor(part, 2);
                part += __shfl_xor(part, 4);
                float lg = part * 0.25f;
                lg = (lg > 0.f) ? lg : 0.2f * lg;        // leaky_relu
                float pa = exp2f(lg * LOG2E);            // exp(logit), f32 safe

                // gate dots for both output cols
                float ev0 = 0.f, ev1 = 0.f;
                ev0 = fdot2(bch(r0A.x), wa[0], ev0);  ev1 = fdot2(bch(r0A.x), wb[0], ev1);
                ev0 = fdot2(bch(r0A.y), wa[1], ev0);  ev1 = fdot2(bch(r0A.y), wb[1], ev1);
                ev0 = fdot2(bch(r0A.z), wa[2], ev0);  ev1 = fdot2(bch(r0A.z), wb[2], ev1);
                ev0 = fdot2(bch(r0A.w), wa[3], ev0);  ev1 = fdot2(bch(r0A.w), wb[3], ev1);
                ev0 = fdot2(bch(r1A.x), wa[4], ev0);  ev1 = fdot2(bch(r1A.x), wb[4], ev1);
                ev0 = fdot2(bch(r1A.y), wa[5], ev0);  ev1 = fdot2(bch(r1A.y), wb[5], ev1);
                ev0 = fdot2(bch(r1A.z), wa[6], ev0);  ev1 = fdot2(bch(r1A.z), wb[6], ev1);
                ev0 = fdot2(bch(r1A.w), wa[7], ev0);  ev1 = fdot2(bch(r1A.w), wb[7], ev1);
                float sg0 = __builtin_amdgcn_rcpf(1.f + exp2f(ev0 * -LOG2E));
                float sg1 = __builtin_amdgcn_rcpf(1.f + exp2f(ev1 * -LOG2E));

                den += pa;
                acc0 = fmaf(pa * sg0, (float)kvA.x, acc0);
                acc1 = fmaf(pa * sg1, (float)kvA.y, acc1);

                // rotate pipeline
                kvA = kvB; r0A = r0B; r1A = r1B; eaA = eaB; ceB = ceC;
            }
        }
        float idn = __builtin_amdgcn_rcpf(den + 1e-9f);
        *(float2*)(out + ((size_t)n << 7) + (lane << 1)) =
            make_float2(acc0 * idn, acc1 * idn);
    }
}

extern "C" void kernel_launch(void* const* d_in, const int* in_sizes, int n_in,
                              void* d_out, int out_size, void* d_ws, size_t ws_size,
                              hipStream_t stream)
{
    const float* x  = (const float*)d_in[0];
    const float* ea = (const float*)d_in[1];
    const float* Wn = (const float*)d_in[2];
    const float* We = (const float*)d_in[3];
    const int*  src = (const int*)d_in[4];
    const int*  dst = (const int*)d_in[5];
    float* out = (float*)d_out;

    int N = in_sizes[0] / 128;   // 50000
    int E = in_sizes[4];         // 800000

    char* ws = (char*)d_ws;
    int2*      csr    = (int2*)ws;                              // E*8   = 6.4MB
    _Float16*  h16    = (_Float16*)(ws + (size_t)E * 8);        // N*256 = 12.8MB
    _Float16*  ea16   = h16 + (size_t)N * 128;                  // E*32  = 25.6MB
    int*       counts = (int*)(ea16 + (size_t)E * 16);          // N
    int*       gcur   = counts + N;                             // 1
    int*       start  = gcur + 1;                               // N
    int*       cursor = start + N;                              // N

    hipMemsetAsync(counts, 0, (size_t)(N + 1) * sizeof(int), stream);

    k_hproj  <<<(N + 63) / 64,   256, 0, stream>>>(x, Wn, h16, N, dst, counts, E);
    k_alloc  <<<(N + 255) / 256, 256, 0, stream>>>(counts, start, cursor, gcur, N);
    k_scatter<<<(E + 255) / 256, 256, 0, stream>>>(src, dst, ea, cursor, csr, ea16, E);
    k_fused2 <<<(N + 7) / 8,     256, 0, stream>>>(h16, ea16, We, csr, start,
                                                   counts, out, N);
}

// Round 8
// 284.158 us; speedup vs baseline: 1.2120x; 1.2120x over previous
//
#include <hip/hip_runtime.h>
#include <math.h>

// ---------------------------------------------------------------------------
// EG-GAT layer v8 — v6 topology + per-edge instruction diet:
//   K1 hproj+hist: h16[N,128] (f16) = x @ W_node; grid-stride degree histogram
//   K2 alloc:      CSR segment starts (wave-aggregated cursor)
//   K3 scatter:    slot-ordered streams: csrc[slot]=src<<8, eac[slot]=ea f16,
//                  ess[slot*8+h]=(ea.cs[h])*0.25*log2e  (colsums via LDS)
//   K4 fused3:     block(128)/node. Per edge: 1 vector load (kv 2B),
//                  uniform slot-stream loads (SMEM-eligible), DPP row_ror
//                  reduce for qk (no LDS-pipe shuffles), fdot2 gate with
//                  -log2e prefolded, den += pa in-loop.
// ---------------------------------------------------------------------------

#define LOG2E 1.44269504088896340736f
#define C_QK  0.36067376022224085f      // 0.25 * log2(e)

typedef _Float16 h2 __attribute__((ext_vector_type(2)));
typedef _Float16 h4 __attribute__((ext_vector_type(4)));

__device__ __forceinline__ float fdot2(h2 a, h2 b, float c) {
    return __builtin_amdgcn_fdot2(a, b, c, false);
}
__device__ __forceinline__ h2 bch(unsigned u) {
    return __builtin_bit_cast(h2, u);
}

// DPP rotate-reduce step: x += rotate_right_within_16_lane_row(x, N)
#define DPP_ROR_ADD(x, ctrl)                                                   \
    x += __builtin_bit_cast(float, __builtin_amdgcn_update_dpp(                \
             0, __builtin_bit_cast(int, x), (ctrl), 0xF, 0xF, false))

// K1: register-blocked GEMM (f16 out) + degree histogram.
__global__ __launch_bounds__(256) void k_hproj(
    const float* __restrict__ x, const float* __restrict__ Wn,
    _Float16* __restrict__ h16, int N,
    const int* __restrict__ dst, int* __restrict__ counts, int E)
{
    int tid = blockIdx.x * 256 + threadIdx.x;
    int tot = gridDim.x * 256;
    for (int e = tid; e < E; e += tot) atomicAdd(counts + dst[e], 1);

    int t  = threadIdx.x;
    int cg = t & 31, rg = t >> 5;
    int c0 = cg * 4;
    int hh = c0 >> 4, d0 = c0 & 15;
    int r0 = blockIdx.x * 64 + rg * 8;
    const float* wbase = Wn + hh * 2048 + d0;

    float acc[8][4];
#pragma unroll
    for (int j = 0; j < 8; ++j)
#pragma unroll
        for (int q = 0; q < 4; ++q) acc[j][q] = 0.f;

    int rr[8];
#pragma unroll
    for (int j = 0; j < 8; ++j) { int n = r0 + j; rr[j] = (n < N) ? n : (N - 1); }

    for (int k0 = 0; k0 < 128; k0 += 4) {
        float4 b0 = *(const float4*)(wbase + (k0 + 0) * 16);
        float4 b1 = *(const float4*)(wbase + (k0 + 1) * 16);
        float4 b2 = *(const float4*)(wbase + (k0 + 2) * 16);
        float4 b3 = *(const float4*)(wbase + (k0 + 3) * 16);
#pragma unroll
        for (int j = 0; j < 8; ++j) {
            float4 a = *(const float4*)(x + (size_t)rr[j] * 128 + k0);
            acc[j][0] += a.x * b0.x + a.y * b1.x + a.z * b2.x + a.w * b3.x;
            acc[j][1] += a.x * b0.y + a.y * b1.y + a.z * b2.y + a.w * b3.y;
            acc[j][2] += a.x * b0.z + a.y * b1.z + a.z * b2.z + a.w * b3.z;
            acc[j][3] += a.x * b0.w + a.y * b1.w + a.z * b2.w + a.w * b3.w;
        }
    }
#pragma unroll
    for (int j = 0; j < 8; ++j) {
        int n = r0 + j;
        if (n < N) {
            h4 v = { (_Float16)acc[j][0], (_Float16)acc[j][1],
                     (_Float16)acc[j][2], (_Float16)acc[j][3] };
            *(h4*)(h16 + (size_t)n * 128 + c0) = v;
        }
    }
}

__global__ __launch_bounds__(256) void k_alloc(
    const int* __restrict__ counts, int* __restrict__ start,
    int* __restrict__ cursor, int* __restrict__ gcur, int N)
{
    int i = blockIdx.x * 256 + threadIdx.x;
    int lane = threadIdx.x & 63;
    int v = (i < N) ? counts[i] : 0;
    int incl = v;
#pragma unroll
    for (int o = 1; o < 64; o <<= 1) {
        int u = __shfl_up(incl, o);
        if (lane >= o) incl += u;
    }
    int total = __shfl(incl, 63);
    int base = 0;
    if (lane == 63) base = atomicAdd(gcur, total);
    base = __shfl(base, 63);
    int st = base + incl - v;
    if (i < N) { start[i] = st; cursor[i] = st; }
}

// K3: bucket edges by dst into slot-ordered streams.
__global__ __launch_bounds__(256) void k_scatter(
    const int* __restrict__ src, const int* __restrict__ dst,
    const float* __restrict__ ea, const float* __restrict__ We,
    int* __restrict__ cursor, int* __restrict__ csrc,
    _Float16* __restrict__ eac, float* __restrict__ ess, int E)
{
    __shared__ float cs[128];            // cs[h*16+i] = sum_d We[h][i][d]
    int t = threadIdx.x;
    if (t < 128) {
        const float4* wr = (const float4*)(We + t * 16);
        float4 w0 = wr[0], w1 = wr[1], w2 = wr[2], w3 = wr[3];
        cs[t] = (w0.x + w0.y + w0.z + w0.w) + (w1.x + w1.y + w1.z + w1.w)
              + (w2.x + w2.y + w2.z + w2.w) + (w3.x + w3.y + w3.z + w3.w);
    }
    __syncthreads();

    int e = blockIdx.x * 256 + t;
    if (e >= E) return;
    int dn = dst[e];
    int pos = atomicAdd(cursor + dn, 1);
    csrc[pos] = src[e] << 8;

    const float4* ap = (const float4*)(ea + (size_t)e * 16);
    float4 a0 = ap[0], a1 = ap[1], a2 = ap[2], a3 = ap[3];

    h4* op = (h4*)(eac + ((size_t)pos << 4));
    op[0] = h4{(_Float16)a0.x, (_Float16)a0.y, (_Float16)a0.z, (_Float16)a0.w};
    op[1] = h4{(_Float16)a1.x, (_Float16)a1.y, (_Float16)a1.z, (_Float16)a1.w};
    op[2] = h4{(_Float16)a2.x, (_Float16)a2.y, (_Float16)a2.z, (_Float16)a2.w};
    op[3] = h4{(_Float16)a3.x, (_Float16)a3.y, (_Float16)a3.z, (_Float16)a3.w};

    float es[8];
#pragma unroll
    for (int h = 0; h < 8; ++h) {
        const float4* cp = (const float4*)(cs + h * 16);
        float4 c0 = cp[0], c1 = cp[1], c2 = cp[2], c3 = cp[3];
        float s = a0.x*c0.x + a0.y*c0.y + a0.z*c0.z + a0.w*c0.w
                + a1.x*c1.x + a1.y*c1.y + a1.z*c1.z + a1.w*c1.w
                + a2.x*c2.x + a2.y*c2.y + a2.z*c2.z + a2.w*c2.w
                + a3.x*c3.x + a3.y*c3.y + a3.z*c3.z + a3.w*c3.w;
        es[h] = s * C_QK;                // pre-scaled for the logit fma
    }
    float4* ep = (float4*)(ess + ((size_t)pos << 3));
    ep[0] = make_float4(es[0], es[1], es[2], es[3]);
    ep[1] = make_float4(es[4], es[5], es[6], es[7]);
}

// K4: block(128) per node; DPP reduce; 1 vector load per edge per lane.
__global__ __launch_bounds__(128) void k_fused3(
    const _Float16* __restrict__ h16, const _Float16* __restrict__ eac,
    const float* __restrict__ ess, const int* __restrict__ csrc,
    const float* __restrict__ We, const int* __restrict__ start,
    const int* __restrict__ counts, float* __restrict__ out, int N)
{
    int n = blockIdx.x;
    if (n >= N) return;
    int c = threadIdx.x;              // c = head*16 + d
    int head = c >> 4, d = c & 15;

    // gate column We[head][:,d], prescaled by -log2e, packed pairs along i
    const float* Wh = We + head * 256;
    h2 w2[8];
#pragma unroll
    for (int i = 0; i < 8; ++i) {
        w2[i] = h2{ (_Float16)(Wh[(2*i)*16 + d]   * -LOG2E),
                    (_Float16)(Wh[(2*i+1)*16 + d] * -LOG2E) };
    }

    float q_c = (float)h16[((size_t)n << 7) + c];
    int deg = __builtin_amdgcn_readfirstlane(counts[n]);
    int s0  = __builtin_amdgcn_readfirstlane(start[n]);
    const char* hb = (const char*)h16;
    unsigned c2 = (unsigned)c << 1;

    float acc = 0.f, den = 0.f;
#pragma unroll 2
    for (int j = 0; j < deg; ++j) {
        int slot = s0 + j;
        unsigned koff = (unsigned)csrc[slot];                    // uniform
        float kv = (float)*(const _Float16*)(hb + koff + c2);    // per-lane 2B
        const uint4* er = (const uint4*)(eac + ((size_t)slot << 4)); // uniform
        uint4 r0 = er[0], r1 = er[1];
        float esv = ess[((size_t)slot << 3) + head];             // head bcast

        // qk: per-lane product, DPP row_ror reduce over the 16-lane head group
        float part = q_c * kv;
        DPP_ROR_ADD(part, 0x128);        // ror:8
        DPP_ROR_ADD(part, 0x124);        // ror:4
        DPP_ROR_ADD(part, 0x122);        // ror:2
        DPP_ROR_ADD(part, 0x121);        // ror:1

        float y  = fmaf(part, C_QK, esv);       // (qk+es)*0.25*log2e
        float lg = fmaxf(y, 0.2f * y);          // leaky_relu (log2 domain)
        float pa = exp2f(lg);                   // exp(logit), f32 safe

        // gate: ev' = -log2e * (ea . We[:,d])
        float ev = 0.f;
        ev = fdot2(bch(r0.x), w2[0], ev);
        ev = fdot2(bch(r0.y), w2[1], ev);
        ev = fdot2(bch(r0.z), w2[2], ev);
        ev = fdot2(bch(r0.w), w2[3], ev);
        ev = fdot2(bch(r1.x), w2[4], ev);
        ev = fdot2(bch(r1.y), w2[5], ev);
        ev = fdot2(bch(r1.z), w2[6], ev);
        ev = fdot2(bch(r1.w), w2[7], ev);
        float sg = __builtin_amdgcn_rcpf(1.f + exp2f(ev));

        den += pa;
        acc = fmaf(pa * sg, kv, acc);
    }
    out[((size_t)n << 7) + c] = acc * __builtin_amdgcn_rcpf(den + 1e-9f);
}

extern "C" void kernel_launch(void* const* d_in, const int* in_sizes, int n_in,
                              void* d_out, int out_size, void* d_ws, size_t ws_size,
                              hipStream_t stream)
{
    const float* x  = (const float*)d_in[0];
    const float* ea = (const float*)d_in[1];
    const float* Wn = (const float*)d_in[2];
    const float* We = (const float*)d_in[3];
    const int*  src = (const int*)d_in[4];
    const int*  dst = (const int*)d_in[5];
    float* out = (float*)d_out;

    int N = in_sizes[0] / 128;   // 50000
    int E = in_sizes[4];         // 800000

    char* ws = (char*)d_ws;
    int*       csrc   = (int*)ws;                               // E*4   = 3.2MB
    _Float16*  eac    = (_Float16*)(ws + (size_t)E * 4);        // E*32  = 25.6MB
    float*     ess    = (float*)(ws + (size_t)E * 36);          // E*32  = 25.6MB
    _Float16*  h16    = (_Float16*)(ws + (size_t)E * 68);       // N*256 = 12.8MB
    int*       counts = (int*)(h16 + (size_t)N * 128);          // N
    int*       gcur   = counts + N;                             // 1
    int*       start  = gcur + 1;                               // N
    int*       cursor = start + N;                              // N

    hipMemsetAsync(counts, 0, (size_t)(N + 1) * sizeof(int), stream);

    k_hproj  <<<(N + 63) / 64,   256, 0, stream>>>(x, Wn, h16, N, dst, counts, E);
    k_alloc  <<<(N + 255) / 256, 256, 0, stream>>>(counts, start, cursor, gcur, N);
    k_scatter<<<(E + 255) / 256, 256, 0, stream>>>(src, dst, ea, We, cursor,
                                                   csrc, eac, ess, E);
    k_fused3 <<<N,               128, 0, stream>>>(h16, eac, ess, csrc, We,
                                                   start, counts, out, N);
}

// Round 9
// 272.219 us; speedup vs baseline: 1.2652x; 1.0439x over previous
//
#include <hip/hip_runtime.h>
#include <math.h>

// ---------------------------------------------------------------------------
// EG-GAT layer v9 — edge-ordered streams, light scatter:
//   K1 prep:   cs colsums (LDS); grid-stride edge loop {hist atomic, ea->ea16,
//              ess[e*8+h]=(ea.cs[h])*0.25*log2e} (all coalesced); then the
//              h16 = x @ W_node register-blocked GEMM (f16 out).
//   K2 alloc:  CSR segment starts (wave-aggregated cursor)
//   K3 scatter: csr[pos] = (e<<5, src<<8)  -- 8B per edge, nothing else
//   K4 fused4: block(128)/node. Per edge: uniform csr/ea/ess loads (random
//              but latency-hidden), per-lane 2B kv gather, DPP row_ror qk
//              reduce, fdot2 gate with -log2e prefolded, den += pa in-loop.
// ---------------------------------------------------------------------------

#define LOG2E 1.44269504088896340736f
#define C_QK  0.36067376022224085f      // 0.25 * log2(e)

typedef _Float16 h2 __attribute__((ext_vector_type(2)));
typedef _Float16 h4 __attribute__((ext_vector_type(4)));

__device__ __forceinline__ float fdot2(h2 a, h2 b, float c) {
    return __builtin_amdgcn_fdot2(a, b, c, false);
}
__device__ __forceinline__ h2 bch(unsigned u) {
    return __builtin_bit_cast(h2, u);
}

// DPP rotate-reduce step: x += rotate_right_within_16_lane_row(x, N)
#define DPP_ROR_ADD(x, ctrl)                                                   \
    x += __builtin_bit_cast(float, __builtin_amdgcn_update_dpp(                \
             0, __builtin_bit_cast(int, x), (ctrl), 0xF, 0xF, false))

// K1: colsums + edge streaming (hist, ea16, ess) + register-blocked GEMM.
__global__ __launch_bounds__(256) void k_prep(
    const float* __restrict__ x, const float* __restrict__ Wn,
    const float* __restrict__ ea, const float* __restrict__ We,
    const int* __restrict__ dst, _Float16* __restrict__ h16,
    _Float16* __restrict__ ea16, float* __restrict__ ess,
    int* __restrict__ counts, int N, int E)
{
    __shared__ float cs[128];            // cs[h*16+i] = sum_d We[h][i][d]
    int t = threadIdx.x;
    if (t < 128) {
        const float4* wr = (const float4*)(We + t * 16);
        float4 w0 = wr[0], w1 = wr[1], w2 = wr[2], w3 = wr[3];
        cs[t] = (w0.x + w0.y + w0.z + w0.w) + (w1.x + w1.y + w1.z + w1.w)
              + (w2.x + w2.y + w2.z + w2.w) + (w3.x + w3.y + w3.z + w3.w);
    }
    __syncthreads();

    // edge-order streaming: histogram + f16 convert + pre-scaled edge-sum
    int tid = blockIdx.x * 256 + t;
    int tot = gridDim.x * 256;
    for (int e = tid; e < E; e += tot) {
        atomicAdd(counts + dst[e], 1);
        const float4* ap = (const float4*)(ea + (size_t)e * 16);
        float4 a0 = ap[0], a1 = ap[1], a2 = ap[2], a3 = ap[3];
        h4* op = (h4*)(ea16 + ((size_t)e << 4));
        op[0] = h4{(_Float16)a0.x, (_Float16)a0.y, (_Float16)a0.z, (_Float16)a0.w};
        op[1] = h4{(_Float16)a1.x, (_Float16)a1.y, (_Float16)a1.z, (_Float16)a1.w};
        op[2] = h4{(_Float16)a2.x, (_Float16)a2.y, (_Float16)a2.z, (_Float16)a2.w};
        op[3] = h4{(_Float16)a3.x, (_Float16)a3.y, (_Float16)a3.z, (_Float16)a3.w};
        float es[8];
#pragma unroll
        for (int h = 0; h < 8; ++h) {
            const float4* cp = (const float4*)(cs + h * 16);
            float4 c0 = cp[0], c1 = cp[1], c2 = cp[2], c3 = cp[3];
            float s = a0.x*c0.x + a0.y*c0.y + a0.z*c0.z + a0.w*c0.w
                    + a1.x*c1.x + a1.y*c1.y + a1.z*c1.z + a1.w*c1.w
                    + a2.x*c2.x + a2.y*c2.y + a2.z*c2.z + a2.w*c2.w
                    + a3.x*c3.x + a3.y*c3.y + a3.z*c3.z + a3.w*c3.w;
            es[h] = s * C_QK;
        }
        float4* ep = (float4*)(ess + ((size_t)e << 3));
        ep[0] = make_float4(es[0], es[1], es[2], es[3]);
        ep[1] = make_float4(es[4], es[5], es[6], es[7]);
    }

    // h-projection GEMM
    int cg = t & 31, rg = t >> 5;
    int c0i = cg * 4;
    int hh = c0i >> 4, d0 = c0i & 15;
    int r0 = blockIdx.x * 64 + rg * 8;
    const float* wbase = Wn + hh * 2048 + d0;

    float acc[8][4];
#pragma unroll
    for (int j = 0; j < 8; ++j)
#pragma unroll
        for (int q = 0; q < 4; ++q) acc[j][q] = 0.f;

    int rr[8];
#pragma unroll
    for (int j = 0; j < 8; ++j) { int n = r0 + j; rr[j] = (n < N) ? n : (N - 1); }

    for (int k0 = 0; k0 < 128; k0 += 4) {
        float4 b0 = *(const float4*)(wbase + (k0 + 0) * 16);
        float4 b1 = *(const float4*)(wbase + (k0 + 1) * 16);
        float4 b2 = *(const float4*)(wbase + (k0 + 2) * 16);
        float4 b3 = *(const float4*)(wbase + (k0 + 3) * 16);
#pragma unroll
        for (int j = 0; j < 8; ++j) {
            float4 a = *(const float4*)(x + (size_t)rr[j] * 128 + k0);
            acc[j][0] += a.x * b0.x + a.y * b1.x + a.z * b2.x + a.w * b3.x;
            acc[j][1] += a.x * b0.y + a.y * b1.y + a.z * b2.y + a.w * b3.y;
            acc[j][2] += a.x * b0.z + a.y * b1.z + a.z * b2.z + a.w * b3.z;
            acc[j][3] += a.x * b0.w + a.y * b1.w + a.z * b2.w + a.w * b3.w;
        }
    }
#pragma unroll
    for (int j = 0; j < 8; ++j) {
        int n = r0 + j;
        if (n < N) {
            h4 v = { (_Float16)acc[j][0], (_Float16)acc[j][1],
                     (_Float16)acc[j][2], (_Float16)acc[j][3] };
            *(h4*)(h16 + (size_t)n * 128 + c0i) = v;
        }
    }
}

__global__ __launch_bounds__(256) void k_alloc(
    const int* __restrict__ counts, int* __restrict__ start,
    int* __restrict__ cursor, int* __restrict__ gcur, int N)
{
    int i = blockIdx.x * 256 + threadIdx.x;
    int lane = threadIdx.x & 63;
    int v = (i < N) ? counts[i] : 0;
    int incl = v;
#pragma unroll
    for (int o = 1; o < 64; o <<= 1) {
        int u = __shfl_up(incl, o);
        if (lane >= o) incl += u;
    }
    int total = __shfl(incl, 63);
    int base = 0;
    if (lane == 63) base = atomicAdd(gcur, total);
    base = __shfl(base, 63);
    int st = base + incl - v;
    if (i < N) { start[i] = st; cursor[i] = st; }
}

// K3: minimal scatter — 8B per edge.
__global__ __launch_bounds__(256) void k_scatter(
    const int* __restrict__ src, const int* __restrict__ dst,
    int* __restrict__ cursor, int2* __restrict__ csr, int E)
{
    int e = blockIdx.x * 256 + threadIdx.x;
    if (e < E) {
        int dn = dst[e];
        int pos = atomicAdd(cursor + dn, 1);
        csr[pos] = make_int2(e << 5, src[e] << 8);
    }
}

// K4: block(128) per node; DPP reduce; edge-indexed uniform streams.
__global__ __launch_bounds__(128) void k_fused4(
    const _Float16* __restrict__ h16, const _Float16* __restrict__ ea16,
    const float* __restrict__ ess, const int2* __restrict__ csr,
    const float* __restrict__ We, const int* __restrict__ start,
    const int* __restrict__ counts, float* __restrict__ out, int N)
{
    int n = blockIdx.x;
    if (n >= N) return;
    int c = threadIdx.x;              // c = head*16 + d
    int head = c >> 4, d = c & 15;

    // gate column We[head][:,d], prescaled by -log2e, packed pairs along i
    const float* Wh = We + head * 256;
    h2 w2[8];
#pragma unroll
    for (int i = 0; i < 8; ++i) {
        w2[i] = h2{ (_Float16)(Wh[(2*i)*16 + d]   * -LOG2E),
                    (_Float16)(Wh[(2*i+1)*16 + d] * -LOG2E) };
    }

    float q_c = (float)h16[((size_t)n << 7) + c];
    int deg = __builtin_amdgcn_readfirstlane(counts[n]);
    int s0  = __builtin_amdgcn_readfirstlane(start[n]);
    const char* hb = (const char*)h16;
    const char* eb = (const char*)ea16;
    const char* sb = (const char*)ess;
    unsigned c2 = (unsigned)c << 1;
    unsigned h4o = (unsigned)head << 2;

    float acc = 0.f, den = 0.f;
#pragma unroll 4
    for (int j = 0; j < deg; ++j) {
        int2 ce = csr[s0 + j];                                   // uniform 8B
        unsigned eoff = (unsigned)ce.x;                          // e<<5
        float kv = (float)*(const _Float16*)(hb + (unsigned)ce.y + c2);
        uint4 r0 = *(const uint4*)(eb + eoff);
        uint4 r1 = *(const uint4*)(eb + eoff + 16);
        float esv = *(const float*)(sb + eoff + h4o);            // ess[e*8+h]

        // qk: per-lane product, DPP row_ror reduce over 16-lane head group
        float part = q_c * kv;
        DPP_ROR_ADD(part, 0x128);        // ror:8
        DPP_ROR_ADD(part, 0x124);        // ror:4
        DPP_ROR_ADD(part, 0x122);        // ror:2
        DPP_ROR_ADD(part, 0x121);        // ror:1

        float y  = fmaf(part, C_QK, esv);       // (qk+es)*0.25*log2e
        float lg = fmaxf(y, 0.2f * y);          // leaky_relu (log2 domain)
        float pa = exp2f(lg);                   // exp(logit), f32 safe

        // gate: ev' = -log2e * (ea . We[:,d])
        float ev = 0.f;
        ev = fdot2(bch(r0.x), w2[0], ev);
        ev = fdot2(bch(r0.y), w2[1], ev);
        ev = fdot2(bch(r0.z), w2[2], ev);
        ev = fdot2(bch(r0.w), w2[3], ev);
        ev = fdot2(bch(r1.x), w2[4], ev);
        ev = fdot2(bch(r1.y), w2[5], ev);
        ev = fdot2(bch(r1.z), w2[6], ev);
        ev = fdot2(bch(r1.w), w2[7], ev);
        float sg = __builtin_amdgcn_rcpf(1.f + exp2f(ev));

        den += pa;
        acc = fmaf(pa * sg, kv, acc);
    }
    out[((size_t)n << 7) + c] = acc * __builtin_amdgcn_rcpf(den + 1e-9f);
}

extern "C" void kernel_launch(void* const* d_in, const int* in_sizes, int n_in,
                              void* d_out, int out_size, void* d_ws, size_t ws_size,
                              hipStream_t stream)
{
    const float* x  = (const float*)d_in[0];
    const float* ea = (const float*)d_in[1];
    const float* Wn = (const float*)d_in[2];
    const float* We = (const float*)d_in[3];
    const int*  src = (const int*)d_in[4];
    const int*  dst = (const int*)d_in[5];
    float* out = (float*)d_out;

    int N = in_sizes[0] / 128;   // 50000
    int E = in_sizes[4];         // 800000

    char* ws = (char*)d_ws;
    int2*      csr    = (int2*)ws;                              // E*8   = 6.4MB
    _Float16*  ea16   = (_Float16*)(ws + (size_t)E * 8);        // E*32  = 25.6MB
    float*     ess    = (float*)(ws + (size_t)E * 40);          // E*32  = 25.6MB
    _Float16*  h16    = (_Float16*)(ws + (size_t)E * 72);       // N*256 = 12.8MB
    int*       counts = (int*)(h16 + (size_t)N * 128);          // N
    int*       gcur   = counts + N;                             // 1
    int*       start  = gcur + 1;                               // N
    int*       cursor = start + N;                              // N

    hipMemsetAsync(counts, 0, (size_t)(N + 1) * sizeof(int), stream);

    k_prep   <<<(N + 63) / 64,   256, 0, stream>>>(x, Wn, ea, We, dst, h16,
                                                   ea16, ess, counts, N, E);
    k_alloc  <<<(N + 255) / 256, 256, 0, stream>>>(counts, start, cursor, gcur, N);
    k_scatter<<<(E + 255) / 256, 256, 0, stream>>>(src, dst, cursor, csr, E);
    k_fused4 <<<N,               128, 0, stream>>>(h16, ea16, ess, csr, We,
                                                   start, counts, out, N);
}

// Round 10
// 257.004 us; speedup vs baseline: 1.3401x; 1.0592x over previous
//
#include <hip/hip_runtime.h>
#include <math.h>

// ---------------------------------------------------------------------------
// EG-GAT layer v10 — parity-split waves, 2 cols/lane, 8-lane DPP reduce:
//   K1 prep:   colsums (LDS); grid-stride edge loop {rank[e]=hist atomic,
//              blob[e] = [ea f16 x16 | ess f32 x8] one 64B line}; h16 GEMM.
//   K2 alloc:  CSR segment starts (wave-aggregated cursor-free)
//   K3 scatter: pos = start[dst] + rank[e]; csr[pos]=(e<<6, src<<8). No atomics.
//   K4 fused5: block(128)/node = 2 waves; wave w handles edges j=w,w+2,...
//              lane = head*8+dd covers cols c = 2*lane, 2*lane+1.
//              qk: packed fdot2 + 3-DPP 8-lane reduce (quad_perm/half_mirror);
//              gate: 16 fdot2 (-log2e prefolded); LDS combine of partials.
// ---------------------------------------------------------------------------

#define LOG2E 1.44269504088896340736f
#define C_QK  0.36067376022224085f      // 0.25 * log2(e)

typedef _Float16 h2 __attribute__((ext_vector_type(2)));
typedef _Float16 h4 __attribute__((ext_vector_type(4)));

__device__ __forceinline__ float fdot2(h2 a, h2 b, float c) {
    return __builtin_amdgcn_fdot2(a, b, c, false);
}
__device__ __forceinline__ h2 bch(unsigned u) {
    return __builtin_bit_cast(h2, u);
}

// x += dpp_permuted(x): quad_perm xor1 = 0xB1, xor2 = 0x4E, half_mirror = 0x141
#define DPP_ADD(x, ctrl)                                                       \
    x += __builtin_bit_cast(float, __builtin_amdgcn_update_dpp(                \
             0, __builtin_bit_cast(int, x), (ctrl), 0xF, 0xF, false))

// K1: colsums + edge streaming (rank, blob) + register-blocked GEMM.
__global__ __launch_bounds__(256) void k_prep(
    const float* __restrict__ x, const float* __restrict__ Wn,
    const float* __restrict__ ea, const float* __restrict__ We,
    const int* __restrict__ dst, _Float16* __restrict__ h16,
    char* __restrict__ blob, int* __restrict__ rank,
    int* __restrict__ counts, int N, int E)
{
    __shared__ float cs[128];            // cs[h*16+i] = sum_d We[h][i][d]
    int t = threadIdx.x;
    if (t < 128) {
        const float4* wr = (const float4*)(We + t * 16);
        float4 w0 = wr[0], w1 = wr[1], w2 = wr[2], w3 = wr[3];
        cs[t] = (w0.x + w0.y + w0.z + w0.w) + (w1.x + w1.y + w1.z + w1.w)
              + (w2.x + w2.y + w2.z + w2.w) + (w3.x + w3.y + w3.z + w3.w);
    }
    __syncthreads();

    int tid = blockIdx.x * 256 + t;
    int tot = gridDim.x * 256;
    for (int e = tid; e < E; e += tot) {
        rank[e] = atomicAdd(counts + dst[e], 1);
        const float4* ap = (const float4*)(ea + (size_t)e * 16);
        float4 a0 = ap[0], a1 = ap[1], a2 = ap[2], a3 = ap[3];
        char* bp = blob + ((size_t)e << 6);
        *(h4*)(bp +  0) = h4{(_Float16)a0.x, (_Float16)a0.y, (_Float16)a0.z, (_Float16)a0.w};
        *(h4*)(bp +  8) = h4{(_Float16)a1.x, (_Float16)a1.y, (_Float16)a1.z, (_Float16)a1.w};
        *(h4*)(bp + 16) = h4{(_Float16)a2.x, (_Float16)a2.y, (_Float16)a2.z, (_Float16)a2.w};
        *(h4*)(bp + 24) = h4{(_Float16)a3.x, (_Float16)a3.y, (_Float16)a3.z, (_Float16)a3.w};
        float es[8];
#pragma unroll
        for (int h = 0; h < 8; ++h) {
            const float4* cp = (const float4*)(cs + h * 16);
            float4 c0 = cp[0], c1 = cp[1], c2 = cp[2], c3 = cp[3];
            float s = a0.x*c0.x + a0.y*c0.y + a0.z*c0.z + a0.w*c0.w
                    + a1.x*c1.x + a1.y*c1.y + a1.z*c1.z + a1.w*c1.w
                    + a2.x*c2.x + a2.y*c2.y + a2.z*c2.z + a2.w*c2.w
                    + a3.x*c3.x + a3.y*c3.y + a3.z*c3.z + a3.w*c3.w;
            es[h] = s * C_QK;
        }
        *(float4*)(bp + 32) = make_float4(es[0], es[1], es[2], es[3]);
        *(float4*)(bp + 48) = make_float4(es[4], es[5], es[6], es[7]);
    }

    // h-projection GEMM
    int cg = t & 31, rg = t >> 5;
    int c0i = cg * 4;
    int hh = c0i >> 4, d0 = c0i & 15;
    int r0 = blockIdx.x * 64 + rg * 8;
    const float* wbase = Wn + hh * 2048 + d0;

    float acc[8][4];
#pragma unroll
    for (int j = 0; j < 8; ++j)
#pragma unroll
        for (int q = 0; q < 4; ++q) acc[j][q] = 0.f;

    int rr[8];
#pragma unroll
    for (int j = 0; j < 8; ++j) { int n = r0 + j; rr[j] = (n < N) ? n : (N - 1); }

    for (int k0 = 0; k0 < 128; k0 += 4) {
        float4 b0 = *(const float4*)(wbase + (k0 + 0) * 16);
        float4 b1 = *(const float4*)(wbase + (k0 + 1) * 16);
        float4 b2 = *(const float4*)(wbase + (k0 + 2) * 16);
        float4 b3 = *(const float4*)(wbase + (k0 + 3) * 16);
#pragma unroll
        for (int j = 0; j < 8; ++j) {
            float4 a = *(const float4*)(x + (size_t)rr[j] * 128 + k0);
            acc[j][0] += a.x * b0.x + a.y * b1.x + a.z * b2.x + a.w * b3.x;
            acc[j][1] += a.x * b0.y + a.y * b1.y + a.z * b2.y + a.w * b3.y;
            acc[j][2] += a.x * b0.z + a.y * b1.z + a.z * b2.z + a.w * b3.z;
            acc[j][3] += a.x * b0.w + a.y * b1.w + a.z * b2.w + a.w * b3.w;
        }
    }
#pragma unroll
    for (int j = 0; j < 8; ++j) {
        int n = r0 + j;
        if (n < N) {
            h4 v = { (_Float16)acc[j][0], (_Float16)acc[j][1],
                     (_Float16)acc[j][2], (_Float16)acc[j][3] };
            *(h4*)(h16 + (size_t)n * 128 + c0i) = v;
        }
    }
}

__global__ __launch_bounds__(256) void k_alloc(
    const int* __restrict__ counts, int* __restrict__ start,
    int* __restrict__ gcur, int N)
{
    int i = blockIdx.x * 256 + threadIdx.x;
    int lane = threadIdx.x & 63;
    int v = (i < N) ? counts[i] : 0;
    int incl = v;
#pragma unroll
    for (int o = 1; o < 64; o <<= 1) {
        int u = __shfl_up(incl, o);
        if (lane >= o) incl += u;
    }
    int total = __shfl(incl, 63);
    int base = 0;
    if (lane == 63) base = atomicAdd(gcur, total);
    base = __shfl(base, 63);
    int st = base + incl - v;
    if (i < N) start[i] = st;
}

// K3: atomic-free scatter — pos = start[dst] + rank.
__global__ __launch_bounds__(256) void k_scatter(
    const int* __restrict__ src, const int* __restrict__ dst,
    const int* __restrict__ rank, const int* __restrict__ start,
    int2* __restrict__ csr, int E)
{
    int e = blockIdx.x * 256 + threadIdx.x;
    if (e < E) {
        int pos = start[dst[e]] + rank[e];
        csr[pos] = make_int2(e << 6, src[e] << 8);
    }
}

// K4: 2 waves/node, parity-split edges, 2 cols/lane, 3-DPP 8-lane reduce.
__global__ __launch_bounds__(128) void k_fused5(
    const _Float16* __restrict__ h16, const char* __restrict__ blob,
    const int2* __restrict__ csr, const float* __restrict__ We,
    const int* __restrict__ start, const int* __restrict__ counts,
    float* __restrict__ out, int N)
{
    __shared__ float sA0[128], sA1[128], sD[128];
    int n = blockIdx.x;
    if (n >= N) return;
    int t = threadIdx.x;
    int lane = t & 63, wid = t >> 6;
    int head = lane >> 3, dd = lane & 7;
    int d0 = dd * 2;                    // cols c0 = 2*lane, c0+1

    // gate columns We[head][:,d0], [:,d0+1], prescaled by -log2e, packed along i
    const float* Wh = We + head * 256;
    h2 wa[8], wb[8];
#pragma unroll
    for (int i = 0; i < 8; ++i) {
        wa[i] = h2{ (_Float16)(Wh[(2*i)*16 + d0]     * -LOG2E),
                    (_Float16)(Wh[(2*i+1)*16 + d0]   * -LOG2E) };
        wb[i] = h2{ (_Float16)(Wh[(2*i)*16 + d0 + 1] * -LOG2E),
                    (_Float16)(Wh[(2*i+1)*16 + d0+1] * -LOG2E) };
    }

    const char* hb = (const char*)h16;
    h2 q2 = *(const h2*)(hb + ((size_t)n << 8) + (lane << 2));
    int deg = __builtin_amdgcn_readfirstlane(counts[n]);
    int s0  = __builtin_amdgcn_readfirstlane(start[n]);
    unsigned l4 = (unsigned)lane << 2;
    unsigned h4o = (unsigned)head << 2;

    float acc0 = 0.f, acc1 = 0.f, den = 0.f;
#pragma unroll 4
    for (int j = wid; j < deg; j += 2) {
        int2 ce = csr[s0 + j];
        h2 kv2 = *(const h2*)(hb + (unsigned)ce.y + l4);
        const char* bp = blob + (unsigned)ce.x;
        uint4 r0 = *(const uint4*)bp;
        uint4 r1 = *(const uint4*)(bp + 16);
        float esv = *(const float*)(bp + 32 + h4o);

        // qk: packed pair product, reduce over the 8-lane (dd) group:
        float part = fdot2(q2, kv2, 0.f);
        DPP_ADD(part, 0xB1);            // quad_perm xor1
        DPP_ADD(part, 0x4E);            // quad_perm xor2
        DPP_ADD(part, 0x141);           // row_half_mirror (xor4 after quad-reduce)

        float y  = fmaf(part, C_QK, esv);      // (qk+es)*0.25*log2e
        float lg = fmaxf(y, 0.2f * y);         // leaky_relu (log2 domain)
        float pa = exp2f(lg);                  // exp(logit), f32 safe

        // gate dots for both cols (weights prefolded with -log2e)
        float ev0 = 0.f, ev1 = 0.f;
        ev0 = fdot2(bch(r0.x), wa[0], ev0);  ev1 = fdot2(bch(r0.x), wb[0], ev1);
        ev0 = fdot2(bch(r0.y), wa[1], ev0);  ev1 = fdot2(bch(r0.y), wb[1], ev1);
        ev0 = fdot2(bch(r0.z), wa[2], ev0);  ev1 = fdot2(bch(r0.z), wb[2], ev1);
        ev0 = fdot2(bch(r0.w), wa[3], ev0);  ev1 = fdot2(bch(r0.w), wb[3], ev1);
        ev0 = fdot2(bch(r1.x), wa[4], ev0);  ev1 = fdot2(bch(r1.x), wb[4], ev1);
        ev0 = fdot2(bch(r1.y), wa[5], ev0);  ev1 = fdot2(bch(r1.y), wb[5], ev1);
        ev0 = fdot2(bch(r1.z), wa[6], ev0);  ev1 = fdot2(bch(r1.z), wb[6], ev1);
        ev0 = fdot2(bch(r1.w), wa[7], ev0);  ev1 = fdot2(bch(r1.w), wb[7], ev1);
        float sg0 = __builtin_amdgcn_rcpf(1.f + exp2f(ev0));
        float sg1 = __builtin_amdgcn_rcpf(1.f + exp2f(ev1));

        den += pa;
        acc0 = fmaf(pa * sg0, (float)kv2.x, acc0);
        acc1 = fmaf(pa * sg1, (float)kv2.y, acc1);
    }

    sA0[t] = acc0; sA1[t] = acc1; sD[t] = den;
    __syncthreads();
    if (wid == 0) {
        float a0 = acc0 + sA0[64 + lane];
        float a1 = acc1 + sA1[64 + lane];
        float dn = den  + sD[64 + lane];
        float idn = __builtin_amdgcn_rcpf(dn + 1e-9f);
        *(float2*)(out + ((size_t)n << 7) + (lane << 1)) =
            make_float2(a0 * idn, a1 * idn);
    }
}

extern "C" void kernel_launch(void* const* d_in, const int* in_sizes, int n_in,
                              void* d_out, int out_size, void* d_ws, size_t ws_size,
                              hipStream_t stream)
{
    const float* x  = (const float*)d_in[0];
    const float* ea = (const float*)d_in[1];
    const float* Wn = (const float*)d_in[2];
    const float* We = (const float*)d_in[3];
    const int*  src = (const int*)d_in[4];
    const int*  dst = (const int*)d_in[5];
    float* out = (float*)d_out;

    int N = in_sizes[0] / 128;   // 50000
    int E = in_sizes[4];         // 800000

    char* ws = (char*)d_ws;
    int2*      csr    = (int2*)ws;                              // E*8   = 6.4MB
    char*      blob   = ws + (size_t)E * 8;                     // E*64  = 51.2MB (64B aligned)
    int*       rank   = (int*)(ws + (size_t)E * 72);            // E*4   = 3.2MB
    _Float16*  h16    = (_Float16*)(ws + (size_t)E * 76);       // N*256 = 12.8MB
    int*       counts = (int*)(h16 + (size_t)N * 128);          // N
    int*       gcur   = counts + N;                             // 1
    int*       start  = gcur + 1;                               // N

    hipMemsetAsync(counts, 0, (size_t)(N + 1) * sizeof(int), stream);

    k_prep   <<<(N + 63) / 64,   256, 0, stream>>>(x, Wn, ea, We, dst, h16,
                                                   blob, rank, counts, N, E);
    k_alloc  <<<(N + 255) / 256, 256, 0, stream>>>(counts, start, gcur, N);
    k_scatter<<<(E + 255) / 256, 256, 0, stream>>>(src, dst, rank, start, csr, E);
    k_fused5 <<<N,               128, 0, stream>>>(h16, blob, csr, We, start,
                                                   counts, out, N);
}

// Round 11
// 231.747 us; speedup vs baseline: 1.4862x; 1.1090x over previous
//
#include <hip/hip_runtime.h>
#include <math.h>

// ---------------------------------------------------------------------------
// EG-GAT layer v11 — node-per-wave fused kernel, amortized prologue:
//   K1 prep:   colsums (LDS); grid-stride edge loop {rank[e]=hist atomic,
//              blob[e] = [ea f16 x16 | ess f32 x8] one 64B line}; h16 GEMM.
//   K2 alloc:  CSR segment starts (wave-aggregated scan, no cursor)
//   K3 scatter: pos = start[dst] + rank[e]; csr[pos]=(e<<6, src<<8). No atomics.
//   K4 fused6: block(128) = 2 waves; block owns 8 nodes; wave w handles
//              nodes b*8+w+2k (k=0..3) WHOLE — no parity split, no LDS
//              combine, weight prologue once per wave. Per edge: packed
//              fdot2 qk + 3-DPP 8-lane reduce, 16 fdot2 gate (-log2e
//              prefolded), den += pa in-loop, float2 row store per node.
// ---------------------------------------------------------------------------

#define LOG2E 1.44269504088896340736f
#define C_QK  0.36067376022224085f      // 0.25 * log2(e)

typedef _Float16 h2 __attribute__((ext_vector_type(2)));
typedef _Float16 h4 __attribute__((ext_vector_type(4)));

__device__ __forceinline__ float fdot2(h2 a, h2 b, float c) {
    return __builtin_amdgcn_fdot2(a, b, c, false);
}
__device__ __forceinline__ h2 bch(unsigned u) {
    return __builtin_bit_cast(h2, u);
}

// x += dpp_permuted(x): quad_perm xor1 = 0xB1, xor2 = 0x4E, half_mirror = 0x141
#define DPP_ADD(x, ctrl)                                                       \
    x += __builtin_bit_cast(float, __builtin_amdgcn_update_dpp(                \
             0, __builtin_bit_cast(int, x), (ctrl), 0xF, 0xF, false))

// K1: colsums + edge streaming (rank, blob) + register-blocked GEMM.
__global__ __launch_bounds__(256) void k_prep(
    const float* __restrict__ x, const float* __restrict__ Wn,
    const float* __restrict__ ea, const float* __restrict__ We,
    const int* __restrict__ dst, _Float16* __restrict__ h16,
    char* __restrict__ blob, int* __restrict__ rank,
    int* __restrict__ counts, int N, int E)
{
    __shared__ float cs[128];            // cs[h*16+i] = sum_d We[h][i][d]
    int t = threadIdx.x;
    if (t < 128) {
        const float4* wr = (const float4*)(We + t * 16);
        float4 w0 = wr[0], w1 = wr[1], w2 = wr[2], w3 = wr[3];
        cs[t] = (w0.x + w0.y + w0.z + w0.w) + (w1.x + w1.y + w1.z + w1.w)
              + (w2.x + w2.y + w2.z + w2.w) + (w3.x + w3.y + w3.z + w3.w);
    }
    __syncthreads();

    int tid = blockIdx.x * 256 + t;
    int tot = gridDim.x * 256;
    for (int e = tid; e < E; e += tot) {
        rank[e] = atomicAdd(counts + dst[e], 1);
        const float4* ap = (const float4*)(ea + (size_t)e * 16);
        float4 a0 = ap[0], a1 = ap[1], a2 = ap[2], a3 = ap[3];
        char* bp = blob + ((size_t)e << 6);
        *(h4*)(bp +  0) = h4{(_Float16)a0.x, (_Float16)a0.y, (_Float16)a0.z, (_Float16)a0.w};
        *(h4*)(bp +  8) = h4{(_Float16)a1.x, (_Float16)a1.y, (_Float16)a1.z, (_Float16)a1.w};
        *(h4*)(bp + 16) = h4{(_Float16)a2.x, (_Float16)a2.y, (_Float16)a2.z, (_Float16)a2.w};
        *(h4*)(bp + 24) = h4{(_Float16)a3.x, (_Float16)a3.y, (_Float16)a3.z, (_Float16)a3.w};
        float es[8];
#pragma unroll
        for (int h = 0; h < 8; ++h) {
            const float4* cp = (const float4*)(cs + h * 16);
            float4 c0 = cp[0], c1 = cp[1], c2 = cp[2], c3 = cp[3];
            float s = a0.x*c0.x + a0.y*c0.y + a0.z*c0.z + a0.w*c0.w
                    + a1.x*c1.x + a1.y*c1.y + a1.z*c1.z + a1.w*c1.w
                    + a2.x*c2.x + a2.y*c2.y + a2.z*c2.z + a2.w*c2.w
                    + a3.x*c3.x + a3.y*c3.y + a3.z*c3.z + a3.w*c3.w;
            es[h] = s * C_QK;
        }
        *(float4*)(bp + 32) = make_float4(es[0], es[1], es[2], es[3]);
        *(float4*)(bp + 48) = make_float4(es[4], es[5], es[6], es[7]);
    }

    // h-projection GEMM
    int cg = t & 31, rg = t >> 5;
    int c0i = cg * 4;
    int hh = c0i >> 4, d0 = c0i & 15;
    int r0 = blockIdx.x * 64 + rg * 8;
    const float* wbase = Wn + hh * 2048 + d0;

    float acc[8][4];
#pragma unroll
    for (int j = 0; j < 8; ++j)
#pragma unroll
        for (int q = 0; q < 4; ++q) acc[j][q] = 0.f;

    int rr[8];
#pragma unroll
    for (int j = 0; j < 8; ++j) { int n = r0 + j; rr[j] = (n < N) ? n : (N - 1); }

    for (int k0 = 0; k0 < 128; k0 += 4) {
        float4 b0 = *(const float4*)(wbase + (k0 + 0) * 16);
        float4 b1 = *(const float4*)(wbase + (k0 + 1) * 16);
        float4 b2 = *(const float4*)(wbase + (k0 + 2) * 16);
        float4 b3 = *(const float4*)(wbase + (k0 + 3) * 16);
#pragma unroll
        for (int j = 0; j < 8; ++j) {
            float4 a = *(const float4*)(x + (size_t)rr[j] * 128 + k0);
            acc[j][0] += a.x * b0.x + a.y * b1.x + a.z * b2.x + a.w * b3.x;
            acc[j][1] += a.x * b0.y + a.y * b1.y + a.z * b2.y + a.w * b3.y;
            acc[j][2] += a.x * b0.z + a.y * b1.z + a.z * b2.z + a.w * b3.z;
            acc[j][3] += a.x * b0.w + a.y * b1.w + a.z * b2.w + a.w * b3.w;
        }
    }
#pragma unroll
    for (int j = 0; j < 8; ++j) {
        int n = r0 + j;
        if (n < N) {
            h4 v = { (_Float16)acc[j][0], (_Float16)acc[j][1],
                     (_Float16)acc[j][2], (_Float16)acc[j][3] };
            *(h4*)(h16 + (size_t)n * 128 + c0i) = v;
        }
    }
}

__global__ __launch_bounds__(256) void k_alloc(
    const int* __restrict__ counts, int* __restrict__ start,
    int* __restrict__ gcur, int N)
{
    int i = blockIdx.x * 256 + threadIdx.x;
    int lane = threadIdx.x & 63;
    int v = (i < N) ? counts[i] : 0;
    int incl = v;
#pragma unroll
    for (int o = 1; o < 64; o <<= 1) {
        int u = __shfl_up(incl, o);
        if (lane >= o) incl += u;
    }
    int total = __shfl(incl, 63);
    int base = 0;
    if (lane == 63) base = atomicAdd(gcur, total);
    base = __shfl(base, 63);
    int st = base + incl - v;
    if (i < N) start[i] = st;
}

// K3: atomic-free scatter — pos = start[dst] + rank.
__global__ __launch_bounds__(256) void k_scatter(
    const int* __restrict__ src, const int* __restrict__ dst,
    const int* __restrict__ rank, const int* __restrict__ start,
    int2* __restrict__ csr, int E)
{
    int e = blockIdx.x * 256 + threadIdx.x;
    if (e < E) {
        int pos = start[dst[e]] + rank[e];
        csr[pos] = make_int2(e << 6, src[e] << 8);
    }
}

// K4: node-per-wave; block owns 8 nodes, wave w does nodes b*8+w+2k.
__global__ __launch_bounds__(128) void k_fused6(
    const _Float16* __restrict__ h16, const char* __restrict__ blob,
    const int2* __restrict__ csr, const float* __restrict__ We,
    const int* __restrict__ start, const int* __restrict__ counts,
    float* __restrict__ out, int N)
{
    int t = threadIdx.x;
    int lane = t & 63, wid = t >> 6;
    int head = lane >> 3, dd = lane & 7;
    int d0 = dd * 2;                    // cols c0 = 2*lane, c0+1

    // prologue once per WAVE: gate columns prescaled by -log2e, packed along i
    const float* Wh = We + head * 256;
    h2 wa[8], wb[8];
#pragma unroll
    for (int i = 0; i < 8; ++i) {
        wa[i] = h2{ (_Float16)(Wh[(2*i)*16 + d0]     * -LOG2E),
                    (_Float16)(Wh[(2*i+1)*16 + d0]   * -LOG2E) };
        wb[i] = h2{ (_Float16)(Wh[(2*i)*16 + d0 + 1] * -LOG2E),
                    (_Float16)(Wh[(2*i+1)*16 + d0+1] * -LOG2E) };
    }

    const char* hb = (const char*)h16;
    unsigned l4 = (unsigned)lane << 2;
    unsigned h4o = (unsigned)head << 2;
    int nb = blockIdx.x * 8 + wid;

#pragma unroll
    for (int k = 0; k < 4; ++k) {
        int n = nb + 2 * k;
        if (n >= N) continue;

        h2 q2 = *(const h2*)(hb + ((size_t)n << 8) + l4);
        int deg = __builtin_amdgcn_readfirstlane(counts[n]);
        int s0  = __builtin_amdgcn_readfirstlane(start[n]);

        float acc0 = 0.f, acc1 = 0.f, den = 0.f;
#pragma unroll 4
        for (int j = 0; j < deg; ++j) {
            int2 ce = csr[s0 + j];
            h2 kv2 = *(const h2*)(hb + (unsigned)ce.y + l4);
            const char* bp = blob + (unsigned)ce.x;
            uint4 r0 = *(const uint4*)bp;
            uint4 r1 = *(const uint4*)(bp + 16);
            float esv = *(const float*)(bp + 32 + h4o);

            // qk: packed pair product, reduce over the 8-lane (dd) group
            float part = fdot2(q2, kv2, 0.f);
            DPP_ADD(part, 0xB1);            // quad_perm xor1
            DPP_ADD(part, 0x4E);            // quad_perm xor2
            DPP_ADD(part, 0x141);           // row_half_mirror

            float y  = fmaf(part, C_QK, esv);      // (qk+es)*0.25*log2e
            float lg = fmaxf(y, 0.2f * y);         // leaky_relu (log2 domain)
            float pa = exp2f(lg);                  // exp(logit), f32 safe

            // gate dots for both cols (weights prefolded with -log2e)
            float ev0 = 0.f, ev1 = 0.f;
            ev0 = fdot2(bch(r0.x), wa[0], ev0);  ev1 = fdot2(bch(r0.x), wb[0], ev1);
            ev0 = fdot2(bch(r0.y), wa[1], ev0);  ev1 = fdot2(bch(r0.y), wb[1], ev1);
            ev0 = fdot2(bch(r0.z), wa[2], ev0);  ev1 = fdot2(bch(r0.z), wb[2], ev1);
            ev0 = fdot2(bch(r0.w), wa[3], ev0);  ev1 = fdot2(bch(r0.w), wb[3], ev1);
            ev0 = fdot2(bch(r1.x), wa[4], ev0);  ev1 = fdot2(bch(r1.x), wb[4], ev1);
            ev0 = fdot2(bch(r1.y), wa[5], ev0);  ev1 = fdot2(bch(r1.y), wb[5], ev1);
            ev0 = fdot2(bch(r1.z), wa[6], ev0);  ev1 = fdot2(bch(r1.z), wb[6], ev1);
            ev0 = fdot2(bch(r1.w), wa[7], ev0);  ev1 = fdot2(bch(r1.w), wb[7], ev1);
            float sg0 = __builtin_amdgcn_rcpf(1.f + exp2f(ev0));
            float sg1 = __builtin_amdgcn_rcpf(1.f + exp2f(ev1));

            den += pa;
            acc0 = fmaf(pa * sg0, (float)kv2.x, acc0);
            acc1 = fmaf(pa * sg1, (float)kv2.y, acc1);
        }
        float idn = __builtin_amdgcn_rcpf(den + 1e-9f);
        *(float2*)(out + ((size_t)n << 7) + (lane << 1)) =
            make_float2(acc0 * idn, acc1 * idn);
    }
}

extern "C" void kernel_launch(void* const* d_in, const int* in_sizes, int n_in,
                              void* d_out, int out_size, void* d_ws, size_t ws_size,
                              hipStream_t stream)
{
    const float* x  = (const float*)d_in[0];
    const float* ea = (const float*)d_in[1];
    const float* Wn = (const float*)d_in[2];
    const float* We = (const float*)d_in[3];
    const int*  src = (const int*)d_in[4];
    const int*  dst = (const int*)d_in[5];
    float* out = (float*)d_out;

    int N = in_sizes[0] / 128;   // 50000
    int E = in_sizes[4];         // 800000

    char* ws = (char*)d_ws;
    int2*      csr    = (int2*)ws;                              // E*8   = 6.4MB
    char*      blob   = ws + (size_t)E * 8;                     // E*64  = 51.2MB
    int*       rank   = (int*)(ws + (size_t)E * 72);            // E*4   = 3.2MB
    _Float16*  h16    = (_Float16*)(ws + (size_t)E * 76);       // N*256 = 12.8MB
    int*       counts = (int*)(h16 + (size_t)N * 128);          // N
    int*       gcur   = counts + N;                             // 1
    int*       start  = gcur + 1;                               // N

    hipMemsetAsync(counts, 0, (size_t)(N + 1) * sizeof(int), stream);

    k_prep   <<<(N + 63) / 64,   256, 0, stream>>>(x, Wn, ea, We, dst, h16,
                                                   blob, rank, counts, N, E);
    k_alloc  <<<(N + 255) / 256, 256, 0, stream>>>(counts, start, gcur, N);
    k_scatter<<<(E + 255) / 256, 256, 0, stream>>>(src, dst, rank, start, csr, E);
    k_fused6 <<<(N + 7) / 8,     128, 0, stream>>>(h16, blob, csr, We, start,
                                                   counts, out, N);
}